// Round 1
// baseline (386.444 us; speedup 1.0000x reference)
//
#include <hip/hip_runtime.h>
#include <math.h>

#define D_FEAT 128

// ---------------------------------------------------------------------------
// K2: histogram of destination nodes (in-degree, excluding self-loop)
// ---------------------------------------------------------------------------
__global__ void count_kernel(const int* __restrict__ dst, int* __restrict__ cnt, int E) {
    int e = blockIdx.x * blockDim.x + threadIdx.x;
    if (e < E) atomicAdd(&cnt[dst[e]], 1);
}

// ---------------------------------------------------------------------------
// K3: single-block exclusive scan of cnt -> offs, plus dinv = rsqrt(cnt+1)
// (self-loop contributes +1 to every node's degree)
// ---------------------------------------------------------------------------
__global__ __launch_bounds__(1024) void scan_kernel(const int* __restrict__ cnt,
                                                    int* __restrict__ offs,
                                                    float* __restrict__ dinv, int n) {
    __shared__ int sdata[1024];
    int t = threadIdx.x;
    int chunk = (n + 1023) >> 10;
    int beg = t * chunk;
    int end = min(n, beg + chunk);
    int sum = 0;
    for (int j = beg; j < end; ++j) sum += cnt[j];
    sdata[t] = sum;
    __syncthreads();
    // Hillis-Steele inclusive scan over 1024 partials
    for (int ofs = 1; ofs < 1024; ofs <<= 1) {
        int v = (t >= ofs) ? sdata[t - ofs] : 0;
        __syncthreads();
        sdata[t] += v;
        __syncthreads();
    }
    int run = (t > 0) ? sdata[t - 1] : 0;  // exclusive base
    for (int j = beg; j < end; ++j) {
        offs[j] = run;
        int c = cnt[j];
        run += c;
        dinv[j] = rsqrtf((float)(c + 1));
    }
    if (t == 1023) offs[n] = run;  // == E
}

// ---------------------------------------------------------------------------
// K4: scatter edges into CSR-by-destination
// ---------------------------------------------------------------------------
__global__ void scatter_kernel(const int* __restrict__ src, const int* __restrict__ dst,
                               const int* __restrict__ offs, int* __restrict__ cur,
                               int* __restrict__ csr, int E) {
    int e = blockIdx.x * blockDim.x + threadIdx.x;
    if (e < E) {
        int d = dst[e];
        int p = atomicAdd(&cur[d], 1);
        csr[offs[d] + p] = src[e];
    }
}

// ---------------------------------------------------------------------------
// K5: per-destination aggregation. One wave (64 lanes) per node, float2/lane.
// agg[i] = dinv[i]^2 * x[i] + sum_{s in nbr(i)} dinv[s]*dinv[i] * x[s]
// ---------------------------------------------------------------------------
__global__ __launch_bounds__(64) void agg_kernel(const float* __restrict__ x,
                                                 const float* __restrict__ dinv,
                                                 const int* __restrict__ offs,
                                                 const int* __restrict__ csr,
                                                 float* __restrict__ agg) {
    int i = blockIdx.x;
    int lane = threadIdx.x;
    const float2* x2 = (const float2*)x;
    float di = dinv[i];
    float2 xs = x2[(size_t)i * 64 + lane];
    float ax = xs.x * di * di;
    float ay = xs.y * di * di;
    int e = offs[i], end = offs[i + 1];
    // unroll by 4 to keep multiple gathers in flight
    for (; e + 4 <= end; e += 4) {
        int s0 = csr[e + 0], s1 = csr[e + 1], s2 = csr[e + 2], s3 = csr[e + 3];
        float w0 = dinv[s0] * di, w1 = dinv[s1] * di, w2 = dinv[s2] * di, w3 = dinv[s3] * di;
        float2 v0 = x2[(size_t)s0 * 64 + lane];
        float2 v1 = x2[(size_t)s1 * 64 + lane];
        float2 v2 = x2[(size_t)s2 * 64 + lane];
        float2 v3 = x2[(size_t)s3 * 64 + lane];
        ax += v0.x * w0; ay += v0.y * w0;
        ax += v1.x * w1; ay += v1.y * w1;
        ax += v2.x * w2; ay += v2.y * w2;
        ax += v3.x * w3; ay += v3.y * w3;
    }
    for (; e < end; ++e) {
        int s = csr[e];
        float w = dinv[s] * di;
        float2 v = x2[(size_t)s * 64 + lane];
        ax += v.x * w; ay += v.y * w;
    }
    float2* a2 = (float2*)agg;
    a2[(size_t)i * 64 + lane] = make_float2(ax, ay);
}

// ---------------------------------------------------------------------------
// K6: out = agg @ W^T + b.  fp32 (no fp32 MFMA on CDNA4 -> vector ALU).
// Block: 256 threads (16x16), 8x8 per-thread tile -> 128 rows x 128 cols/block.
// K chunked at 32 with transposed LDS staging; PAD=132 keeps float4 alignment
// (528 B row pitch, 16B-multiple) and breaks staging-write bank clustering.
// ---------------------------------------------------------------------------
#define KC 32
#define PAD 132
__global__ __launch_bounds__(256) void gemm_kernel(const float* __restrict__ A,
                                                   const float* __restrict__ W,
                                                   const float* __restrict__ bias,
                                                   float* __restrict__ out, int n) {
    __shared__ float Bs[KC * PAD];  // [k][o]  (W transposed)
    __shared__ float As[KC * PAD];  // [k][r]  (agg transposed)
    int t = threadIdx.x;
    int tx = t & 15;   // 16 col-groups * 8 cols = 128 cols
    int ty = t >> 4;   // 16 row-groups * 8 rows = 128 rows
    int r0 = blockIdx.x * 128;

    float acc[8][8];
#pragma unroll
    for (int i = 0; i < 8; ++i)
#pragma unroll
        for (int j = 0; j < 8; ++j) acc[i][j] = 0.0f;

    for (int kk = 0; kk < D_FEAT; kk += KC) {
#pragma unroll
        for (int it = 0; it < 16; ++it) {
            int idx = t + it * 256;   // 0..4095
            int o = idx >> 5;         // 0..127
            int kq = idx & 31;
            Bs[kq * PAD + o] = W[o * D_FEAT + kk + kq];
            int row = r0 + o;
            As[kq * PAD + o] = (row < n) ? A[(size_t)row * D_FEAT + kk + kq] : 0.0f;
        }
        __syncthreads();
#pragma unroll
        for (int k = 0; k < KC; ++k) {
            float4 a0 = *(const float4*)&As[k * PAD + ty * 8];
            float4 a1 = *(const float4*)&As[k * PAD + ty * 8 + 4];
            float4 b0 = *(const float4*)&Bs[k * PAD + tx * 8];
            float4 b1 = *(const float4*)&Bs[k * PAD + tx * 8 + 4];
            float a[8] = {a0.x, a0.y, a0.z, a0.w, a1.x, a1.y, a1.z, a1.w};
            float b[8] = {b0.x, b0.y, b0.z, b0.w, b1.x, b1.y, b1.z, b1.w};
#pragma unroll
            for (int i = 0; i < 8; ++i)
#pragma unroll
                for (int j = 0; j < 8; ++j) acc[i][j] += a[i] * b[j];
        }
        __syncthreads();
    }

    float bv[8];
#pragma unroll
    for (int j = 0; j < 8; ++j) bv[j] = bias[tx * 8 + j];
#pragma unroll
    for (int i = 0; i < 8; ++i) {
        int row = r0 + ty * 8 + i;
        if (row < n) {
            float* op = out + (size_t)row * D_FEAT + tx * 8;
#pragma unroll
            for (int j = 0; j < 8; ++j) op[j] = acc[i][j] + bv[j];
        }
    }
}

extern "C" void kernel_launch(void* const* d_in, const int* in_sizes, int n_in,
                              void* d_out, int out_size, void* d_ws, size_t ws_size,
                              hipStream_t stream) {
    const float* x = (const float*)d_in[0];
    const int* ei = (const int*)d_in[1];
    const float* W = (const float*)d_in[2];
    const float* b = (const float*)d_in[3];
    float* out = (float*)d_out;

    int n = in_sizes[0] / D_FEAT;   // 50000
    int E = in_sizes[1] / 2;        // 800000
    const int* src = ei;
    const int* dst = ei + E;

    // workspace layout (ws is re-poisoned 0xAA each call -> re-init everything)
    char* ws = (char*)d_ws;
    size_t off = 0;
    auto alloc = [&](size_t bytes) {
        char* p = ws + off;
        off = (off + bytes + 255) & ~(size_t)255;
        return p;
    };
    int* cnt = (int*)alloc((size_t)n * 4);
    int* cur = (int*)alloc((size_t)n * 4);
    int* offs = (int*)alloc((size_t)(n + 1) * 4);
    float* dinv = (float*)alloc((size_t)n * 4);
    int* csr = (int*)alloc((size_t)E * 4);
    float* agg = (float*)alloc((size_t)n * D_FEAT * 4);
    (void)ws_size;

    // zero the two atomic counter arrays (cnt, cur are the first 2 regions)
    hipMemsetAsync(d_ws, 0, (size_t)((char*)offs - (char*)d_ws), stream);

    int tb = 256;
    count_kernel<<<(E + tb - 1) / tb, tb, 0, stream>>>(dst, cnt, E);
    scan_kernel<<<1, 1024, 0, stream>>>(cnt, offs, dinv, n);
    scatter_kernel<<<(E + tb - 1) / tb, tb, 0, stream>>>(src, dst, offs, cur, csr, E);
    agg_kernel<<<n, 64, 0, stream>>>(x, dinv, offs, csr, agg);
    gemm_kernel<<<(n + 127) / 128, 256, 0, stream>>>(agg, W, b, out, n);
}

// Round 2
// 289.766 us; speedup vs baseline: 1.3336x; 1.3336x over previous
//
#include <hip/hip_runtime.h>
#include <math.h>

#define D_FEAT 128
#define SCAN_TILE 256   // elements per block in the decomposed scan

// ---------------------------------------------------------------------------
// K1: histogram of destination nodes (in-degree, excluding self-loop)
// ---------------------------------------------------------------------------
__global__ void count_kernel(const int* __restrict__ dst, int* __restrict__ cnt, int E) {
    int e = blockIdx.x * blockDim.x + threadIdx.x;
    if (e < E) atomicAdd(&cnt[dst[e]], 1);
}

// ---------------------------------------------------------------------------
// K2a: per-block partial sums of cnt (SCAN_TILE elements / 256-thread block)
// ---------------------------------------------------------------------------
__global__ __launch_bounds__(256) void block_sums_kernel(const int* __restrict__ cnt,
                                                         int* __restrict__ bsum, int n) {
    __shared__ int red[4];
    int t = threadIdx.x;
    int i = blockIdx.x * SCAN_TILE + t;
    int v = (i < n) ? cnt[i] : 0;
    // wave reduce (64 lanes)
    for (int ofs = 32; ofs > 0; ofs >>= 1) v += __shfl_down(v, ofs, 64);
    if ((t & 63) == 0) red[t >> 6] = v;
    __syncthreads();
    if (t == 0) bsum[blockIdx.x] = red[0] + red[1] + red[2] + red[3];
}

// ---------------------------------------------------------------------------
// K2b: single-block exclusive scan of the (<=256) block partials
// ---------------------------------------------------------------------------
__global__ __launch_bounds__(256) void scan_partials_kernel(const int* __restrict__ bsum,
                                                            int* __restrict__ bbase,
                                                            int* __restrict__ offs,
                                                            int nblocks, int n, int E) {
    __shared__ int s[256];
    int t = threadIdx.x;
    int v = (t < nblocks) ? bsum[t] : 0;
    s[t] = v;
    __syncthreads();
    for (int ofs = 1; ofs < 256; ofs <<= 1) {
        int u = (t >= ofs) ? s[t - ofs] : 0;
        __syncthreads();
        s[t] += u;
        __syncthreads();
    }
    if (t < nblocks) bbase[t] = s[t] - v;  // exclusive
    if (t == 0) offs[n] = E;
}

// ---------------------------------------------------------------------------
// K2c: per-block LDS scan -> offs; fused dinv = rsqrt(cnt+1)
// ---------------------------------------------------------------------------
__global__ __launch_bounds__(256) void scan_finalize_kernel(const int* __restrict__ cnt,
                                                            const int* __restrict__ bbase,
                                                            int* __restrict__ offs,
                                                            float* __restrict__ dinv, int n) {
    __shared__ int s[256];
    int t = threadIdx.x;
    int i = blockIdx.x * SCAN_TILE + t;
    int c = (i < n) ? cnt[i] : 0;
    s[t] = c;
    __syncthreads();
    for (int ofs = 1; ofs < 256; ofs <<= 1) {
        int u = (t >= ofs) ? s[t - ofs] : 0;
        __syncthreads();
        s[t] += u;
        __syncthreads();
    }
    if (i < n) {
        offs[i] = bbase[blockIdx.x] + s[t] - c;  // exclusive prefix
        dinv[i] = rsqrtf((float)(c + 1));
    }
}

// ---------------------------------------------------------------------------
// K3: scatter edges into CSR-by-destination. cnt is consumed as a countdown
// cursor (it is dead after K2c), so no separate `cur` array or memset.
// ---------------------------------------------------------------------------
__global__ void scatter_kernel(const int* __restrict__ src, const int* __restrict__ dst,
                               const int* __restrict__ offs, int* __restrict__ cnt,
                               int* __restrict__ csr, int E) {
    int e = blockIdx.x * blockDim.x + threadIdx.x;
    if (e < E) {
        int d = dst[e];
        int p = atomicAdd(&cnt[d], -1);        // old value: count .. 1
        csr[offs[d] + p - 1] = src[e];
    }
}

// ---------------------------------------------------------------------------
// K4: per-destination aggregation. One wave per node, 4 nodes per 256-thread
// block (1-wave blocks cap resident waves/CU via the workgroup-slot limit).
// agg[i] = dinv[i]^2 * x[i] + sum_{s in nbr(i)} dinv[s]*dinv[i] * x[s]
// ---------------------------------------------------------------------------
__global__ __launch_bounds__(256) void agg_kernel(const float* __restrict__ x,
                                                  const float* __restrict__ dinv,
                                                  const int* __restrict__ offs,
                                                  const int* __restrict__ csr,
                                                  float* __restrict__ agg, int n) {
    int i = blockIdx.x * 4 + (threadIdx.x >> 6);
    if (i >= n) return;
    int lane = threadIdx.x & 63;
    const float2* x2 = (const float2*)x;
    float di = dinv[i];
    float2 xs = x2[(size_t)i * 64 + lane];
    float ax = xs.x * di * di;
    float ay = xs.y * di * di;
    int e = offs[i], end = offs[i + 1];
    for (; e + 4 <= end; e += 4) {
        int s0 = csr[e + 0], s1 = csr[e + 1], s2 = csr[e + 2], s3 = csr[e + 3];
        float w0 = dinv[s0] * di, w1 = dinv[s1] * di, w2 = dinv[s2] * di, w3 = dinv[s3] * di;
        float2 v0 = x2[(size_t)s0 * 64 + lane];
        float2 v1 = x2[(size_t)s1 * 64 + lane];
        float2 v2 = x2[(size_t)s2 * 64 + lane];
        float2 v3 = x2[(size_t)s3 * 64 + lane];
        ax += v0.x * w0; ay += v0.y * w0;
        ax += v1.x * w1; ay += v1.y * w1;
        ax += v2.x * w2; ay += v2.y * w2;
        ax += v3.x * w3; ay += v3.y * w3;
    }
    for (; e < end; ++e) {
        int s = csr[e];
        float w = dinv[s] * di;
        float2 v = x2[(size_t)s * 64 + lane];
        ax += v.x * w; ay += v.y * w;
    }
    float2* a2 = (float2*)agg;
    a2[(size_t)i * 64 + lane] = make_float2(ax, ay);
}

// ---------------------------------------------------------------------------
// K5: out = agg @ W^T + b.  fp32 vector ALU (no fp32 MFMA on CDNA4).
// 256 threads (16x16), 8x8/thread -> 128x128 tile. K chunked at 32, LDS
// transposed staging, PAD=132 keeps float4 alignment + breaks bank clustering.
// ---------------------------------------------------------------------------
#define KC 32
#define PAD 132
__global__ __launch_bounds__(256) void gemm_kernel(const float* __restrict__ A,
                                                   const float* __restrict__ W,
                                                   const float* __restrict__ bias,
                                                   float* __restrict__ out, int n) {
    __shared__ float Bs[KC * PAD];  // [k][o]  (W transposed)
    __shared__ float As[KC * PAD];  // [k][r]  (agg transposed)
    int t = threadIdx.x;
    int tx = t & 15;
    int ty = t >> 4;
    int r0 = blockIdx.x * 128;

    float acc[8][8];
#pragma unroll
    for (int i = 0; i < 8; ++i)
#pragma unroll
        for (int j = 0; j < 8; ++j) acc[i][j] = 0.0f;

    for (int kk = 0; kk < D_FEAT; kk += KC) {
#pragma unroll
        for (int it = 0; it < 16; ++it) {
            int idx = t + it * 256;   // 0..4095
            int o = idx >> 5;         // 0..127
            int kq = idx & 31;
            Bs[kq * PAD + o] = W[o * D_FEAT + kk + kq];
            int row = r0 + o;
            As[kq * PAD + o] = (row < n) ? A[(size_t)row * D_FEAT + kk + kq] : 0.0f;
        }
        __syncthreads();
#pragma unroll
        for (int k = 0; k < KC; ++k) {
            float4 a0 = *(const float4*)&As[k * PAD + ty * 8];
            float4 a1 = *(const float4*)&As[k * PAD + ty * 8 + 4];
            float4 b0 = *(const float4*)&Bs[k * PAD + tx * 8];
            float4 b1 = *(const float4*)&Bs[k * PAD + tx * 8 + 4];
            float a[8] = {a0.x, a0.y, a0.z, a0.w, a1.x, a1.y, a1.z, a1.w};
            float b[8] = {b0.x, b0.y, b0.z, b0.w, b1.x, b1.y, b1.z, b1.w};
#pragma unroll
            for (int i = 0; i < 8; ++i)
#pragma unroll
                for (int j = 0; j < 8; ++j) acc[i][j] += a[i] * b[j];
        }
        __syncthreads();
    }

    float bv[8];
#pragma unroll
    for (int j = 0; j < 8; ++j) bv[j] = bias[tx * 8 + j];
#pragma unroll
    for (int i = 0; i < 8; ++i) {
        int row = r0 + ty * 8 + i;
        if (row < n) {
            float* op = out + (size_t)row * D_FEAT + tx * 8;
#pragma unroll
            for (int j = 0; j < 8; ++j) op[j] = acc[i][j] + bv[j];
        }
    }
}

extern "C" void kernel_launch(void* const* d_in, const int* in_sizes, int n_in,
                              void* d_out, int out_size, void* d_ws, size_t ws_size,
                              hipStream_t stream) {
    const float* x = (const float*)d_in[0];
    const int* ei = (const int*)d_in[1];
    const float* W = (const float*)d_in[2];
    const float* b = (const float*)d_in[3];
    float* out = (float*)d_out;

    int n = in_sizes[0] / D_FEAT;   // 50000
    int E = in_sizes[1] / 2;        // 800000
    const int* src = ei;
    const int* dst = ei + E;

    int nblk = (n + SCAN_TILE - 1) / SCAN_TILE;   // 196 <= 256

    // workspace layout (ws is re-poisoned 0xAA each call -> re-init everything)
    char* ws = (char*)d_ws;
    size_t off = 0;
    auto alloc = [&](size_t bytes) {
        char* p = ws + off;
        off = (off + bytes + 255) & ~(size_t)255;
        return p;
    };
    int* cnt = (int*)alloc((size_t)n * 4);          // must be first (memset)
    int* offs = (int*)alloc((size_t)(n + 1) * 4);
    float* dinv = (float*)alloc((size_t)n * 4);
    int* bsum = (int*)alloc((size_t)nblk * 4);
    int* bbase = (int*)alloc((size_t)nblk * 4);
    int* csr = (int*)alloc((size_t)E * 4);
    float* agg = (float*)alloc((size_t)n * D_FEAT * 4);
    (void)ws_size;

    hipMemsetAsync(cnt, 0, (size_t)n * 4, stream);

    int tb = 256;
    count_kernel<<<(E + tb - 1) / tb, tb, 0, stream>>>(dst, cnt, E);
    block_sums_kernel<<<nblk, 256, 0, stream>>>(cnt, bsum, n);
    scan_partials_kernel<<<1, 256, 0, stream>>>(bsum, bbase, offs, nblk, n, E);
    scan_finalize_kernel<<<nblk, 256, 0, stream>>>(cnt, bbase, offs, dinv, n);
    scatter_kernel<<<(E + tb - 1) / tb, tb, 0, stream>>>(src, dst, offs, cnt, csr, E);
    agg_kernel<<<(n + 3) / 4, 256, 0, stream>>>(x, dinv, offs, csr, agg, n);
    gemm_kernel<<<(n + 127) / 128, 256, 0, stream>>>(agg, W, b, out, n);
}

// Round 3
// 249.145 us; speedup vs baseline: 1.5511x; 1.1630x over previous
//
#include <hip/hip_runtime.h>
#include <math.h>

#define D_FEAT 128
#define SCAN_TILE 256   // elements per block in the decomposed scan

// ---------------------------------------------------------------------------
// K1: histogram of destination nodes (in-degree, excluding self-loop)
// ---------------------------------------------------------------------------
__global__ void count_kernel(const int* __restrict__ dst, int* __restrict__ cnt, int E) {
    int e = blockIdx.x * blockDim.x + threadIdx.x;
    if (e < E) atomicAdd(&cnt[dst[e]], 1);
}

// ---------------------------------------------------------------------------
// K2a: per-block partial sums of cnt (SCAN_TILE elements / 256-thread block)
// ---------------------------------------------------------------------------
__global__ __launch_bounds__(256) void block_sums_kernel(const int* __restrict__ cnt,
                                                         int* __restrict__ bsum, int n) {
    __shared__ int red[4];
    int t = threadIdx.x;
    int i = blockIdx.x * SCAN_TILE + t;
    int v = (i < n) ? cnt[i] : 0;
    for (int ofs = 32; ofs > 0; ofs >>= 1) v += __shfl_down(v, ofs, 64);
    if ((t & 63) == 0) red[t >> 6] = v;
    __syncthreads();
    if (t == 0) bsum[blockIdx.x] = red[0] + red[1] + red[2] + red[3];
}

// ---------------------------------------------------------------------------
// K2b: single-block exclusive scan of the (<=256) block partials
// ---------------------------------------------------------------------------
__global__ __launch_bounds__(256) void scan_partials_kernel(const int* __restrict__ bsum,
                                                            int* __restrict__ bbase,
                                                            int* __restrict__ offs,
                                                            int nblocks, int n, int E) {
    __shared__ int s[256];
    int t = threadIdx.x;
    int v = (t < nblocks) ? bsum[t] : 0;
    s[t] = v;
    __syncthreads();
    for (int ofs = 1; ofs < 256; ofs <<= 1) {
        int u = (t >= ofs) ? s[t - ofs] : 0;
        __syncthreads();
        s[t] += u;
        __syncthreads();
    }
    if (t < nblocks) bbase[t] = s[t] - v;  // exclusive
    if (t == 0) offs[n] = E;
}

// ---------------------------------------------------------------------------
// K2c: per-block LDS scan -> offs; fused dinv = rsqrt(cnt+1)
// ---------------------------------------------------------------------------
__global__ __launch_bounds__(256) void scan_finalize_kernel(const int* __restrict__ cnt,
                                                            const int* __restrict__ bbase,
                                                            int* __restrict__ offs,
                                                            float* __restrict__ dinv, int n) {
    __shared__ int s[256];
    int t = threadIdx.x;
    int i = blockIdx.x * SCAN_TILE + t;
    int c = (i < n) ? cnt[i] : 0;
    s[t] = c;
    __syncthreads();
    for (int ofs = 1; ofs < 256; ofs <<= 1) {
        int u = (t >= ofs) ? s[t - ofs] : 0;
        __syncthreads();
        s[t] += u;
        __syncthreads();
    }
    if (i < n) {
        offs[i] = bbase[blockIdx.x] + s[t] - c;  // exclusive prefix
        dinv[i] = rsqrtf((float)(c + 1));
    }
}

// ---------------------------------------------------------------------------
// K3: scatter edges into CSR-by-destination. cnt is consumed as a countdown
// cursor (it is dead after K2c), so no separate `cur` array or memset.
// ---------------------------------------------------------------------------
__global__ void scatter_kernel(const int* __restrict__ src, const int* __restrict__ dst,
                               const int* __restrict__ offs, int* __restrict__ cnt,
                               int* __restrict__ csr, int E) {
    int e = blockIdx.x * blockDim.x + threadIdx.x;
    if (e < E) {
        int d = dst[e];
        int p = atomicAdd(&cnt[d], -1);        // old value: count .. 1
        csr[offs[d] + p - 1] = src[e];
    }
}

// ---------------------------------------------------------------------------
// K4: per-destination aggregation. One wave per node, 4 nodes per 256-thread
// block. Gather chain unrolled by 8 to keep more loads in flight.
// ---------------------------------------------------------------------------
__global__ __launch_bounds__(256) void agg_kernel(const float* __restrict__ x,
                                                  const float* __restrict__ dinv,
                                                  const int* __restrict__ offs,
                                                  const int* __restrict__ csr,
                                                  float* __restrict__ agg, int n) {
    int i = blockIdx.x * 4 + (threadIdx.x >> 6);
    if (i >= n) return;
    int lane = threadIdx.x & 63;
    const float2* x2 = (const float2*)x;
    float di = dinv[i];
    float2 xs = x2[(size_t)i * 64 + lane];
    float ax = xs.x * di * di;
    float ay = xs.y * di * di;
    int e = offs[i], end = offs[i + 1];
    for (; e + 8 <= end; e += 8) {
        int s[8];
#pragma unroll
        for (int j = 0; j < 8; ++j) s[j] = csr[e + j];
        float w[8];
#pragma unroll
        for (int j = 0; j < 8; ++j) w[j] = dinv[s[j]] * di;
        float2 v[8];
#pragma unroll
        for (int j = 0; j < 8; ++j) v[j] = x2[(size_t)s[j] * 64 + lane];
#pragma unroll
        for (int j = 0; j < 8; ++j) { ax += v[j].x * w[j]; ay += v[j].y * w[j]; }
    }
    for (; e < end; ++e) {
        int s = csr[e];
        float w = dinv[s] * di;
        float2 v = x2[(size_t)s * 64 + lane];
        ax += v.x * w; ay += v.y * w;
    }
    float2* a2 = (float2*)agg;
    a2[(size_t)i * 64 + lane] = make_float2(ax, ay);
}

// ---------------------------------------------------------------------------
// K5: out = agg @ W^T + b.  fp32 vector ALU (no fp32 MFMA on CDNA4).
// 64x64 tile per 256-thread block, 4x4 per thread. Grid = 2*ceil(n/64) = 1564
// blocks (~6 blocks/CU of work vs R2's 1.5 -> latency actually hidden).
// LDS 32 KB -> ~5 resident blocks/CU. K chunked at 64, [k][r] transposed
// staging so the inner loop is 2x ds_read_b128 + 16 FMA per k.
// ---------------------------------------------------------------------------
#define TK 64
#define LP 64   // LDS row pitch (floats); 64*4B=256B keeps float4 alignment
__global__ __launch_bounds__(256) void gemm_kernel(const float* __restrict__ A,
                                                   const float* __restrict__ W,
                                                   const float* __restrict__ bias,
                                                   float* __restrict__ out, int n) {
    __shared__ float As[TK * LP];  // [k][r]
    __shared__ float Bs[TK * LP];  // [k][c]
    int t = threadIdx.x;
    int r0 = (blockIdx.x >> 1) * 64;
    int c0 = (blockIdx.x & 1) * 64;
    int tx = t & 15;   // 16 col-groups * 4 cols
    int ty = t >> 4;   // 16 row-groups * 4 rows

    int lrow = t >> 2;        // 0..63: tile row (A) / tile col (W) staged
    int lk = (t & 3) * 16;    // k-segment within chunk

    float acc[4][4];
#pragma unroll
    for (int i = 0; i < 4; ++i)
#pragma unroll
        for (int j = 0; j < 4; ++j) acc[i][j] = 0.0f;

    int grow = r0 + lrow;
    const float* Ap = A + (size_t)grow * D_FEAT + lk;
    const float* Wp = W + (size_t)(c0 + lrow) * D_FEAT + lk;

    for (int kk = 0; kk < D_FEAT; kk += TK) {
#pragma unroll
        for (int j = 0; j < 4; ++j) {
            float4 av = (grow < n) ? *(const float4*)(Ap + kk + j * 4)
                                   : make_float4(0.f, 0.f, 0.f, 0.f);
            float4 wv = *(const float4*)(Wp + kk + j * 4);
            int kb = lk + j * 4;
            As[(kb + 0) * LP + lrow] = av.x;
            As[(kb + 1) * LP + lrow] = av.y;
            As[(kb + 2) * LP + lrow] = av.z;
            As[(kb + 3) * LP + lrow] = av.w;
            Bs[(kb + 0) * LP + lrow] = wv.x;
            Bs[(kb + 1) * LP + lrow] = wv.y;
            Bs[(kb + 2) * LP + lrow] = wv.z;
            Bs[(kb + 3) * LP + lrow] = wv.w;
        }
        __syncthreads();
#pragma unroll 8
        for (int k = 0; k < TK; ++k) {
            float4 a = *(const float4*)&As[k * LP + ty * 4];
            float4 b = *(const float4*)&Bs[k * LP + tx * 4];
            acc[0][0] += a.x * b.x; acc[0][1] += a.x * b.y;
            acc[0][2] += a.x * b.z; acc[0][3] += a.x * b.w;
            acc[1][0] += a.y * b.x; acc[1][1] += a.y * b.y;
            acc[1][2] += a.y * b.z; acc[1][3] += a.y * b.w;
            acc[2][0] += a.z * b.x; acc[2][1] += a.z * b.y;
            acc[2][2] += a.z * b.z; acc[2][3] += a.z * b.w;
            acc[3][0] += a.w * b.x; acc[3][1] += a.w * b.y;
            acc[3][2] += a.w * b.z; acc[3][3] += a.w * b.w;
        }
        __syncthreads();
    }

    float4 bv = *(const float4*)&bias[c0 + tx * 4];
#pragma unroll
    for (int i = 0; i < 4; ++i) {
        int row = r0 + ty * 4 + i;
        if (row < n) {
            float4 o;
            o.x = acc[i][0] + bv.x;
            o.y = acc[i][1] + bv.y;
            o.z = acc[i][2] + bv.z;
            o.w = acc[i][3] + bv.w;
            *(float4*)(out + (size_t)row * D_FEAT + c0 + tx * 4) = o;
        }
    }
}

extern "C" void kernel_launch(void* const* d_in, const int* in_sizes, int n_in,
                              void* d_out, int out_size, void* d_ws, size_t ws_size,
                              hipStream_t stream) {
    const float* x = (const float*)d_in[0];
    const int* ei = (const int*)d_in[1];
    const float* W = (const float*)d_in[2];
    const float* b = (const float*)d_in[3];
    float* out = (float*)d_out;

    int n = in_sizes[0] / D_FEAT;   // 50000
    int E = in_sizes[1] / 2;        // 800000
    const int* src = ei;
    const int* dst = ei + E;

    int nblk = (n + SCAN_TILE - 1) / SCAN_TILE;   // 196 <= 256

    char* ws = (char*)d_ws;
    size_t off = 0;
    auto alloc = [&](size_t bytes) {
        char* p = ws + off;
        off = (off + bytes + 255) & ~(size_t)255;
        return p;
    };
    int* cnt = (int*)alloc((size_t)n * 4);          // must be first (memset)
    int* offs = (int*)alloc((size_t)(n + 1) * 4);
    float* dinv = (float*)alloc((size_t)n * 4);
    int* bsum = (int*)alloc((size_t)nblk * 4);
    int* bbase = (int*)alloc((size_t)nblk * 4);
    int* csr = (int*)alloc((size_t)E * 4);
    float* agg = (float*)alloc((size_t)n * D_FEAT * 4);
    (void)ws_size;

    hipMemsetAsync(cnt, 0, (size_t)n * 4, stream);

    int tb = 256;
    count_kernel<<<(E + tb - 1) / tb, tb, 0, stream>>>(dst, cnt, E);
    block_sums_kernel<<<nblk, 256, 0, stream>>>(cnt, bsum, n);
    scan_partials_kernel<<<1, 256, 0, stream>>>(bsum, bbase, offs, nblk, n, E);
    scan_finalize_kernel<<<nblk, 256, 0, stream>>>(cnt, bbase, offs, dinv, n);
    scatter_kernel<<<(E + tb - 1) / tb, tb, 0, stream>>>(src, dst, offs, cnt, csr, E);
    agg_kernel<<<(n + 3) / 4, 256, 0, stream>>>(x, dinv, offs, csr, agg, n);
    gemm_kernel<<<((n + 63) / 64) * 2, 256, 0, stream>>>(agg, W, b, out, n);
}